// Round 6
// baseline (158.211 us; speedup 1.0000x reference)
//
#include <hip/hip_runtime.h>
#include <math.h>

// Problem constants (MultiHeadAttention_15341623181946)
#define NB 8          // batch
#define SS 1024       // sequence
#define NH 16         // heads
#define DK 64         // head dim
#define EE 1024       // NH*DK
#define DMOD 1024     // d_model

using bf16x8 = __attribute__((ext_vector_type(8))) short;   // 8 bf16 = 4 VGPR
using f32x4  = __attribute__((ext_vector_type(4))) float;   // MFMA acc

__device__ __forceinline__ unsigned short f2bf(float f) {
    unsigned u = __builtin_bit_cast(unsigned, f);
    u += 0x7FFFu + ((u >> 16) & 1u);        // round-to-nearest-even
    return (unsigned short)(u >> 16);
}

__device__ __forceinline__ float exp2_hw(float x) {
#if __has_builtin(__builtin_amdgcn_exp2f)
    return __builtin_amdgcn_exp2f(x);
#else
    float r; asm("v_exp_f32 %0, %1" : "=v"(r) : "v"(x)); return r;
#endif
}

__device__ __forceinline__ unsigned cvt_pk_bf16(float lo, float hi) {
    unsigned r;
    asm("v_cvt_pk_bf16_f32 %0, %1, %2" : "=v"(r) : "v"(lo), "v"(hi));
    return r;
}

// Async global->LDS, 16B per lane. LDS dest must be wave-uniform base;
// HW writes base + lane*16. Global src is per-lane.
__device__ __forceinline__ void gld16(const void* g, void* l) {
    __builtin_amdgcn_global_load_lds(
        (const __attribute__((address_space(1))) void*)g,
        (__attribute__((address_space(3))) void*)l, 16, 0, 0);
}

// ---------------------------------------------------------------------------
// Batched f32 -> bf16 conversion for all tensors that feed MFMA.
// z: 0=W1(1M) 1=W2(1M) 2=q(512K) 3=k 4=v 5=Wq(64K). grid (512, 6).
// ---------------------------------------------------------------------------
__global__ __launch_bounds__(256) void cvt_all(
    const float* __restrict__ W1, const float* __restrict__ W2,
    const float* __restrict__ q, const float* __restrict__ k,
    const float* __restrict__ v, const float* __restrict__ Wq,
    unsigned short* __restrict__ W1b, unsigned short* __restrict__ W2b,
    unsigned short* __restrict__ qb, unsigned short* __restrict__ kb,
    unsigned short* __restrict__ vb, unsigned short* __restrict__ Wqb)
{
    const int z = blockIdx.y;
    const float* s; unsigned short* d; int n;
    switch (z) {
        case 0:  s = W1; d = W1b; n = 1048576; break;
        case 1:  s = W2; d = W2b; n = 1048576; break;
        case 2:  s = q;  d = qb;  n = 524288;  break;
        case 3:  s = k;  d = kb;  n = 524288;  break;
        case 4:  s = v;  d = vb;  n = 524288;  break;
        default: s = Wq; d = Wqb; n = 65536;   break;
    }
    const int i = (blockIdx.x * 256 + threadIdx.x) * 8;
    if (i >= n) return;
    const float4 a = *(const float4*)(s + i);
    const float4 b = *(const float4*)(s + i + 4);
    bf16x8 o;
    o[0]=(short)f2bf(a.x); o[1]=(short)f2bf(a.y); o[2]=(short)f2bf(a.z); o[3]=(short)f2bf(a.w);
    o[4]=(short)f2bf(b.x); o[5]=(short)f2bf(b.y); o[6]=(short)f2bf(b.z); o[7]=(short)f2bf(b.w);
    *(bf16x8*)(d + i) = o;
}

// ---------------------------------------------------------------------------
// Projection GEMM, bf16 MFMA, K=64. z = 0:q (scaled), 1:k, 2:v (TRANSPOSED).
// z<2 : C[b][h][s][d]  = (X @ Wq^T + bq) * sc
// z==2: C[b][h][d][s]  =  X @ Wq^T + bq        (V stored pre-transposed)
// 128x128 tile, 4 waves (2x2 of 64x64), single K-step.
// Staging via global_load_lds (tiles are fully contiguous: rows are K=64).
// ---------------------------------------------------------------------------
__global__ __launch_bounds__(256) void proj_mfma(
    const unsigned short* __restrict__ qb, const unsigned short* __restrict__ kb,
    const unsigned short* __restrict__ vb, const unsigned short* __restrict__ Wb,
    const float* __restrict__ bias, unsigned short* __restrict__ Cbase,
    float qscale)
{
    __shared__ __align__(16) unsigned short As[128 * 64];
    __shared__ __align__(16) unsigned short Bs[128 * 64];
    const int z = blockIdx.z;
    const unsigned short* X = (z == 0) ? qb : (z == 1) ? kb : vb;
    unsigned short* C = Cbase + (size_t)z * 8388608;
    const float sc = (z == 0) ? qscale : 1.0f;
    const int tid  = threadIdx.x;
    const int lane = tid & 63;
    const int w = tid >> 6, wm = w >> 1, wn = w & 1;
    const int n0 = blockIdx.x * 128, m0 = blockIdx.y * 128;
    const int lr = lane & 15, lg = lane >> 4;

    // async stage: A-tile and B-tile are each 16KB contiguous
    #pragma unroll
    for (int p = 0; p < 4; ++p) {
        const int c = p * 256 + tid;
        const int lb = (p * 256 + (tid & ~63)) * 8;   // wave-uniform LDS elem base
        gld16(X  + (size_t)m0 * DK + (size_t)c * 8, As + lb);
        gld16(Wb + (size_t)n0 * DK + (size_t)c * 8, Bs + lb);
    }
    __syncthreads();

    f32x4 acc[4][4] = {};
    #pragma unroll
    for (int kk = 0; kk < 2; ++kk) {
        bf16x8 af[4], bfr[4];
        #pragma unroll
        for (int mf = 0; mf < 4; ++mf)
            af[mf] = *(const bf16x8*)&As[(wm * 64 + mf * 16 + lr) * 64 + kk * 32 + lg * 8];
        #pragma unroll
        for (int nf = 0; nf < 4; ++nf)
            bfr[nf] = *(const bf16x8*)&Bs[(wn * 64 + nf * 16 + lr) * 64 + kk * 32 + lg * 8];
        #pragma unroll
        for (int mf = 0; mf < 4; ++mf)
            #pragma unroll
            for (int nf = 0; nf < 4; ++nf)
                acc[mf][nf] = __builtin_amdgcn_mfma_f32_16x16x32_bf16(
                    af[mf], bfr[nf], acc[mf][nf], 0, 0, 0);
    }

    #pragma unroll
    for (int nf = 0; nf < 4; ++nf) {
        const int n = n0 + wn * 64 + nf * 16 + lr;
        const float bb = bias[n];
        #pragma unroll
        for (int mf = 0; mf < 4; ++mf)
            #pragma unroll
            for (int r = 0; r < 4; ++r) {
                const int mr = m0 + wm * 64 + mf * 16 + lg * 4 + r;
                const int bh = (mr >> 10) * NH + (n >> 6);
                const int s  = mr & 1023, d = n & 63;
                const size_t idx = (z == 2)
                    ? (size_t)bh * 65536 + (size_t)d * 1024 + s     // [b][h][d][s]
                    : (size_t)bh * 65536 + (size_t)s * 64 + d;      // [b][h][s][d]
                C[idx] = f2bf((acc[mf][nf][r] + bb) * sc);
            }
    }
}

// ---------------------------------------------------------------------------
// Flash attention v6: v5 structure (LDS-staged K/V + T2 chunk-XOR swizzle +
// T14 async stage split + swapped QK^T + base-2 softmax + defer-max),
// minus the Q LDS tile: Q fragments are loop-invariant -> read once from
// global. LDS 33.8 -> 25.6 KB => 6 blocks/CU (was 4).
// ---------------------------------------------------------------------------
__global__ __launch_bounds__(256) void attn_v6(
    const unsigned short* __restrict__ Qp, const unsigned short* __restrict__ Kp,
    const unsigned short* __restrict__ Vt, unsigned short* __restrict__ Y)
{
    __shared__ __align__(16) unsigned short Ks[64 * 64];
    __shared__ __align__(16) unsigned short Vs[64 * 64];   // rows are d, cols k
    __shared__ __align__(16) unsigned short Ps[4][16][72]; // per-wave P [q][k]
    const int tid  = threadIdx.x;
    const int lane = tid & 63;
    const int w    = tid >> 6;
    const int q0   = blockIdx.x * 64;
    const size_t base = (size_t)(blockIdx.z * NH + blockIdx.y) * (SS * DK);
    const int lr = lane & 15, lg = lane >> 4;
    const int lg4 = lg * 4;

    // staging geometry: two 16B chunks per thread (tile = 512 chunks)
    const int c0 = tid,       r0 = c0 >> 3, h0 = c0 & 7;
    const int c1 = 256 + tid, r1 = c1 >> 3, h1 = c1 & 7;
    const int lds0 = r0 * 64 + ((h0 ^ (r0 & 7)) << 3);   // swizzled ushort idx
    const int lds1 = r1 * 64 + ((h1 ^ (r1 & 7)) << 3);

    // ---- K/V tile 0 -> regs -> LDS ----
    const unsigned short* kbase = Kp + base;
    const unsigned short* vbase = Vt + base;
    bf16x8 kA = *(const bf16x8*)(kbase + (size_t)r0 * DK + h0 * 8);
    bf16x8 kB = *(const bf16x8*)(kbase + (size_t)r1 * DK + h1 * 8);
    bf16x8 vA = *(const bf16x8*)(vbase + (size_t)r0 * SS + h0 * 8);
    bf16x8 vB = *(const bf16x8*)(vbase + (size_t)r1 * SS + h1 * 8);
    *(bf16x8*)&Ks[lds0] = kA; *(bf16x8*)&Ks[lds1] = kB;
    *(bf16x8*)&Vs[lds0] = vA; *(bf16x8*)&Vs[lds1] = vB;

    // ---- Q fragments direct from global (loop-invariant) ----
    const unsigned short* qptr = Qp + base + (size_t)(q0 + w * 16 + lr) * DK + lg * 8;
    const bf16x8 bQ0 = *(const bf16x8*)qptr;
    const bf16x8 bQ1 = *(const bf16x8*)(qptr + 32);

    __syncthreads();

    float m = -1e30f, l = 0.0f;       // per-lane state for q = lr (x4 copies)
    f32x4 oacc[4] = {};               // O[q=lg4+r][d=16*d0+lr]

    for (int kt = 0; kt < 16; ++kt) {
        // --- T14: issue next tile's global loads before compute ---
        if (kt < 15) {
            const int s1 = (kt + 1) * 64;
            kA = *(const bf16x8*)(kbase + (size_t)(s1 + r0) * DK + h0 * 8);
            kB = *(const bf16x8*)(kbase + (size_t)(s1 + r1) * DK + h1 * 8);
            vA = *(const bf16x8*)(vbase + (size_t)r0 * SS + s1 + h0 * 8);
            vB = *(const bf16x8*)(vbase + (size_t)r1 * SS + s1 + h1 * 8);
        }

        // --- QK^T (swapped): sacc[nb] = S^T[16 k-rows][16 q] ---
        f32x4 sacc[4];
        #pragma unroll
        for (int nb = 0; nb < 4; ++nb) {
            const int krow = nb * 16 + lr;
            const bf16x8 aK0 = *(const bf16x8*)&Ks[krow * 64 + ((lg       ^ (lr & 7)) << 3)];
            const bf16x8 aK1 = *(const bf16x8*)&Ks[krow * 64 + (((4 + lg) ^ (lr & 7)) << 3)];
            f32x4 z = {};
            z = __builtin_amdgcn_mfma_f32_16x16x32_bf16(aK0, bQ0, z, 0, 0, 0);
            z = __builtin_amdgcn_mfma_f32_16x16x32_bf16(aK1, bQ1, z, 0, 0, 0);
            sacc[nb] = z;
        }

        // --- V fragments (swizzled read; independent of softmax) ---
        bf16x8 bV[2][4];
        #pragma unroll
        for (int kk = 0; kk < 2; ++kk)
            #pragma unroll
            for (int d0 = 0; d0 < 4; ++d0) {
                const int vrow = d0 * 16 + lr;
                bV[kk][d0] = *(const bf16x8*)&Vs[vrow * 64 + (((kk * 4 + lg) ^ (lr & 7)) << 3)];
            }

        // --- online softmax over k (base-2; scale pre-folded into Q) ---
        float mx = sacc[0][0];
        #pragma unroll
        for (int nb = 0; nb < 4; ++nb)
            #pragma unroll
            for (int r = 0; r < 4; ++r)
                mx = fmaxf(mx, sacc[nb][r]);
        mx = fmaxf(mx, __shfl_xor(mx, 16));
        mx = fmaxf(mx, __shfl_xor(mx, 32));

        if (__any(mx > m + 8.0f)) {            // T13 defer-max, THR=8 (base-2)
            const float mn = fmaxf(m, mx);
            const float alpha = exp2_hw(m - mn);
            m = mn;
            l *= alpha;
            #pragma unroll
            for (int r = 0; r < 4; ++r) {
                const float ar = __shfl(alpha, lg4 + r, 16);
                #pragma unroll
                for (int d0 = 0; d0 < 4; ++d0) oacc[d0][r] *= ar;
            }
        }

        float p[4][4];
        float ls = 0.0f;
        #pragma unroll
        for (int nb = 0; nb < 4; ++nb)
            #pragma unroll
            for (int r = 0; r < 4; ++r) {
                const float pv = exp2_hw(sacc[nb][r] - m);
                p[nb][r] = pv;
                ls += pv;
            }
        ls += __shfl_xor(ls, 16);
        ls += __shfl_xor(ls, 32);
        l += ls;

        // --- pack P to bf16, wide LDS stores: P[q=lr][k=16nb+lg4 .. +3] ---
        #pragma unroll
        for (int nb = 0; nb < 4; ++nb) {
            uint2 pw;
            pw.x = cvt_pk_bf16(p[nb][0], p[nb][1]);
            pw.y = cvt_pk_bf16(p[nb][2], p[nb][3]);
            *(uint2*)&Ps[w][lr][nb * 16 + lg4] = pw;
        }
        // same-wave write->read: compiler inserts lgkmcnt wait, no barrier

        // --- PV: O[16q][64d] += P[16][64] x V[64][64] ---
        #pragma unroll
        for (int kk = 0; kk < 2; ++kk) {
            const bf16x8 aP = *(const bf16x8*)&Ps[w][lr][kk * 32 + lg * 8];
            #pragma unroll
            for (int d0 = 0; d0 < 4; ++d0)
                oacc[d0] = __builtin_amdgcn_mfma_f32_16x16x32_bf16(aP, bV[kk][d0], oacc[d0], 0, 0, 0);
        }

        // --- T14 tail: publish prefetched tile to LDS ---
        if (kt < 15) {
            __syncthreads();                   // all waves done reading tiles
            *(bf16x8*)&Ks[lds0] = kA; *(bf16x8*)&Ks[lds1] = kB;
            *(bf16x8*)&Vs[lds0] = vA; *(bf16x8*)&Vs[lds1] = vB;
            __syncthreads();                   // tiles ready
        }
    }

    // epilogue: Y[b][s][h*64+d] bf16; 1/l broadcast per row
    const float linv = 1.0f / l;
    #pragma unroll
    for (int r = 0; r < 4; ++r) {
        const float lri = __shfl(linv, lg4 + r, 16);
        const int qr = q0 + w * 16 + lg4 + r;
        unsigned short* dst = Y + (size_t)(blockIdx.z * SS + qr) * EE + blockIdx.y * DK;
        #pragma unroll
        for (int d0 = 0; d0 < 4; ++d0)
            dst[d0 * 16 + lr] = f2bf(oacc[d0][r] * lri);
    }
}

// ---------------------------------------------------------------------------
// MLP GEMM, bf16 MFMA, m97-structure: C = A[M,K] @ B[N,K]^T + bias (+ReLU)
// 128x128 tile, 4 waves (2x2 of 64x64), K-step 64, LINEAR LDS staged via
// global_load_lds width=16 (2-barrier loop; T2 swizzle null at 128s+2ph).
// ---------------------------------------------------------------------------
template<bool RELU, bool OUT_BF16>
__global__ __launch_bounds__(256) void mlp_gemm(
    const unsigned short* __restrict__ A, const unsigned short* __restrict__ B,
    const float* __restrict__ bias, void* __restrict__ Cv)
{
    constexpr int K = 1024, N = 1024;
    __shared__ __align__(16) unsigned short As[128 * 64];
    __shared__ __align__(16) unsigned short Bs[128 * 64];
    const int tid  = threadIdx.x;
    const int lane = tid & 63;
    const int w = tid >> 6, wm = w >> 1, wn = w & 1;
    const int n0 = blockIdx.x * 128, m0 = blockIdx.y * 128;
    const int lr = lane & 15, lg = lane >> 4;

    f32x4 acc[4][4] = {};

    for (int kt = 0; kt < K; kt += 64) {
        __syncthreads();                       // previous tile's readers done
        #pragma unroll
        for (int p = 0; p < 4; ++p) {
            const int c = p * 256 + tid;       // chunk 0..1023
            const int row = c >> 3, col = (c & 7) * 8;
            const int lb = (p * 256 + (tid & ~63)) * 8;   // wave-uniform LDS base
            gld16(A + (size_t)(m0 + row) * K + kt + col, As + lb);
            gld16(B + (size_t)(n0 + row) * K + kt + col, Bs + lb);
        }
        __syncthreads();                       // vmcnt(0) drain + publish
        #pragma unroll
        for (int kk = 0; kk < 2; ++kk) {
            bf16x8 af[4], bfr[4];
            #pragma unroll
            for (int mf = 0; mf < 4; ++mf)
                af[mf] = *(const bf16x8*)&As[(wm * 64 + mf * 16 + lr) * 64 + kk * 32 + lg * 8];
            #pragma unroll
            for (int nf = 0; nf < 4; ++nf)
                bfr[nf] = *(const bf16x8*)&Bs[(wn * 64 + nf * 16 + lr) * 64 + kk * 32 + lg * 8];
            #pragma unroll
            for (int mf = 0; mf < 4; ++mf)
                #pragma unroll
                for (int nf = 0; nf < 4; ++nf)
                    acc[mf][nf] = __builtin_amdgcn_mfma_f32_16x16x32_bf16(
                        af[mf], bfr[nf], acc[mf][nf], 0, 0, 0);
        }
    }

    #pragma unroll
    for (int nf = 0; nf < 4; ++nf) {
        const int cc = n0 + wn * 64 + nf * 16 + lr;
        const float bb = bias[cc];
        #pragma unroll
        for (int mf = 0; mf < 4; ++mf) {
            #pragma unroll
            for (int r = 0; r < 4; ++r) {
                float x = acc[mf][nf][r] + bb;
                if (RELU) x = fmaxf(x, 0.0f);
                const size_t rr = (size_t)(m0 + wm * 64 + mf * 16 + lg * 4 + r);
                if (OUT_BF16) ((unsigned short*)Cv)[rr * N + cc] = f2bf(x);
                else          ((float*)Cv)[rr * N + cc] = x;
            }
        }
    }
}

// ---------------------------------------------------------------------------
// Workspace layout (ushort elements):
//   Qp : [0        , 8388608 )  -> reused as H1 after attention
//   Kp : [8388608  , 16777216)
//   Vt : [16777216 , 25165824)  (projection z=2 writes [b][h][d][s] directly)
//   Y  : [25165824 , 33554432)
//   W1b: [33554432 , 34603008)
//   W2b: [34603008 , 35651584)
//   qb : [35651584 , 36175872)
//   kb : [36175872 , 36700160)
//   vb : [36700160 , 37224448)
//   Wqb: [37224448 , 37289984)   total ~74.6 MB
// ---------------------------------------------------------------------------
extern "C" void kernel_launch(void* const* d_in, const int* in_sizes, int n_in,
                              void* d_out, int out_size, void* d_ws, size_t ws_size,
                              hipStream_t stream) {
    const float* q  = (const float*)d_in[0];
    const float* k  = (const float*)d_in[1];
    const float* v  = (const float*)d_in[2];
    const float* Wq = (const float*)d_in[3];
    const float* bq = (const float*)d_in[4];
    const float* W1 = (const float*)d_in[5];
    const float* b1 = (const float*)d_in[6];
    const float* W2 = (const float*)d_in[7];
    const float* b2 = (const float*)d_in[8];

    unsigned short* wsu = (unsigned short*)d_ws;
    unsigned short* Qp  = wsu;
    unsigned short* Kp  = wsu + (size_t)8388608;
    unsigned short* Vt  = wsu + (size_t)16777216;
    unsigned short* Y   = wsu + (size_t)25165824;
    unsigned short* W1b = wsu + (size_t)33554432;
    unsigned short* W2b = wsu + (size_t)34603008;
    unsigned short* qb  = wsu + (size_t)35651584;
    unsigned short* kb  = wsu + (size_t)36175872;
    unsigned short* vb  = wsu + (size_t)36700160;
    unsigned short* Wqb = wsu + (size_t)37224448;
    unsigned short* H1  = Qp;   // Qp dead after attention

    dim3 blk(256);

    cvt_all<<<dim3(512, 6), blk, 0, stream>>>(W1, W2, q, k, v, Wq,
                                              W1b, W2b, qb, kb, vb, Wqb);

    // folds 1/sqrt(dk)=0.125 and log2(e) into Q so attn uses v_exp_f32 directly
    const float qscale = 0.125f * 1.44269504088896340736f;
    proj_mfma<<<dim3(8, 64, 3), blk, 0, stream>>>(qb, kb, vb, Wqb, bq, Qp, qscale);

    attn_v6<<<dim3(16, 16, 8), blk, 0, stream>>>(Qp, Kp, Vt, Y);

    mlp_gemm<true,  true ><<<dim3(8, 64), blk, 0, stream>>>(Y,  W1b, b1, H1);
    mlp_gemm<false, false><<<dim3(8, 64), blk, 0, stream>>>(H1, W2b, b2, d_out);
}

// Round 8
// 158.206 us; speedup vs baseline: 1.0000x; 1.0000x over previous
//
#include <hip/hip_runtime.h>
#include <math.h>

// Problem constants (MultiHeadAttention_15341623181946)
#define NB 8          // batch
#define SS 1024       // sequence
#define NH 16         // heads
#define DK 64         // head dim
#define EE 1024       // NH*DK
#define DMOD 1024     // d_model

using bf16x8 = __attribute__((ext_vector_type(8))) short;   // 8 bf16 = 4 VGPR
using f32x4  = __attribute__((ext_vector_type(4))) float;   // MFMA acc

__device__ __forceinline__ unsigned short f2bf(float f) {
    unsigned u = __builtin_bit_cast(unsigned, f);
    u += 0x7FFFu + ((u >> 16) & 1u);        // round-to-nearest-even
    return (unsigned short)(u >> 16);
}

__device__ __forceinline__ float exp2_hw(float x) {
#if __has_builtin(__builtin_amdgcn_exp2f)
    return __builtin_amdgcn_exp2f(x);
#else
    float r; asm("v_exp_f32 %0, %1" : "=v"(r) : "v"(x)); return r;
#endif
}

__device__ __forceinline__ unsigned cvt_pk_bf16(float lo, float hi) {
    unsigned r;
    asm("v_cvt_pk_bf16_f32 %0, %1, %2" : "=v"(r) : "v"(lo), "v"(hi));
    return r;
}

// Async global->LDS, 16B per lane. LDS dest must be wave-uniform base;
// HW writes base + lane*16. Global src is per-lane.
__device__ __forceinline__ void gld16(const void* g, void* l) {
    __builtin_amdgcn_global_load_lds(
        (const __attribute__((address_space(1))) void*)g,
        (__attribute__((address_space(3))) void*)l, 16, 0, 0);
}

// ---------------------------------------------------------------------------
// Batched f32 -> bf16 conversion for all tensors that feed MFMA.
// z: 0=W1(1M) 1=W2(1M) 2=q(512K) 3=k 4=v 5=Wq(64K). grid (512, 6).
// ---------------------------------------------------------------------------
__global__ __launch_bounds__(256) void cvt_all(
    const float* __restrict__ W1, const float* __restrict__ W2,
    const float* __restrict__ q, const float* __restrict__ k,
    const float* __restrict__ v, const float* __restrict__ Wq,
    unsigned short* __restrict__ W1b, unsigned short* __restrict__ W2b,
    unsigned short* __restrict__ qb, unsigned short* __restrict__ kb,
    unsigned short* __restrict__ vb, unsigned short* __restrict__ Wqb)
{
    const int z = blockIdx.y;
    const float* s; unsigned short* d; int n;
    switch (z) {
        case 0:  s = W1; d = W1b; n = 1048576; break;
        case 1:  s = W2; d = W2b; n = 1048576; break;
        case 2:  s = q;  d = qb;  n = 524288;  break;
        case 3:  s = k;  d = kb;  n = 524288;  break;
        case 4:  s = v;  d = vb;  n = 524288;  break;
        default: s = Wq; d = Wqb; n = 65536;   break;
    }
    const int i = (blockIdx.x * 256 + threadIdx.x) * 8;
    if (i >= n) return;
    const float4 a = *(const float4*)(s + i);
    const float4 b = *(const float4*)(s + i + 4);
    bf16x8 o;
    o[0]=(short)f2bf(a.x); o[1]=(short)f2bf(a.y); o[2]=(short)f2bf(a.z); o[3]=(short)f2bf(a.w);
    o[4]=(short)f2bf(b.x); o[5]=(short)f2bf(b.y); o[6]=(short)f2bf(b.z); o[7]=(short)f2bf(b.w);
    *(bf16x8*)(d + i) = o;
}

// ---------------------------------------------------------------------------
// Projection GEMM, bf16 MFMA, K=64. z = 0:q (scaled), 1:k, 2:v (TRANSPOSED).
// z<2 : C[b][h][s][d]  = (X @ Wq^T + bq) * sc
// z==2: C[b][h][d][s]  =  X @ Wq^T + bq        (V stored pre-transposed)
// 128x128 tile, 4 waves (2x2 of 64x64), single K-step, global_load_lds stage.
// ---------------------------------------------------------------------------
__global__ __launch_bounds__(256) void proj_mfma(
    const unsigned short* __restrict__ qb, const unsigned short* __restrict__ kb,
    const unsigned short* __restrict__ vb, const unsigned short* __restrict__ Wb,
    const float* __restrict__ bias, unsigned short* __restrict__ Cbase,
    float qscale)
{
    __shared__ __align__(16) unsigned short As[128 * 64];
    __shared__ __align__(16) unsigned short Bs[128 * 64];
    const int z = blockIdx.z;
    const unsigned short* X = (z == 0) ? qb : (z == 1) ? kb : vb;
    unsigned short* C = Cbase + (size_t)z * 8388608;
    const float sc = (z == 0) ? qscale : 1.0f;
    const int tid  = threadIdx.x;
    const int lane = tid & 63;
    const int w = tid >> 6, wm = w >> 1, wn = w & 1;
    const int n0 = blockIdx.x * 128, m0 = blockIdx.y * 128;
    const int lr = lane & 15, lg = lane >> 4;

    #pragma unroll
    for (int p = 0; p < 4; ++p) {
        const int c = p * 256 + tid;
        const int lb = (p * 256 + (tid & ~63)) * 8;   // wave-uniform LDS elem base
        gld16(X  + (size_t)m0 * DK + (size_t)c * 8, As + lb);
        gld16(Wb + (size_t)n0 * DK + (size_t)c * 8, Bs + lb);
    }
    __syncthreads();

    f32x4 acc[4][4] = {};
    #pragma unroll
    for (int kk = 0; kk < 2; ++kk) {
        bf16x8 af[4], bfr[4];
        #pragma unroll
        for (int mf = 0; mf < 4; ++mf)
            af[mf] = *(const bf16x8*)&As[(wm * 64 + mf * 16 + lr) * 64 + kk * 32 + lg * 8];
        #pragma unroll
        for (int nf = 0; nf < 4; ++nf)
            bfr[nf] = *(const bf16x8*)&Bs[(wn * 64 + nf * 16 + lr) * 64 + kk * 32 + lg * 8];
        #pragma unroll
        for (int mf = 0; mf < 4; ++mf)
            #pragma unroll
            for (int nf = 0; nf < 4; ++nf)
                acc[mf][nf] = __builtin_amdgcn_mfma_f32_16x16x32_bf16(
                    af[mf], bfr[nf], acc[mf][nf], 0, 0, 0);
    }

    #pragma unroll
    for (int nf = 0; nf < 4; ++nf) {
        const int n = n0 + wn * 64 + nf * 16 + lr;
        const float bb = bias[n];
        #pragma unroll
        for (int mf = 0; mf < 4; ++mf)
            #pragma unroll
            for (int r = 0; r < 4; ++r) {
                const int mr = m0 + wm * 64 + mf * 16 + lg * 4 + r;
                const int bh = (mr >> 10) * NH + (n >> 6);
                const int s  = mr & 1023, d = n & 63;
                const size_t idx = (z == 2)
                    ? (size_t)bh * 65536 + (size_t)d * 1024 + s     // [b][h][d][s]
                    : (size_t)bh * 65536 + (size_t)s * 64 + d;      // [b][h][s][d]
                C[idx] = f2bf((acc[mf][nf][r] + bb) * sc);
            }
    }
}

// ---------------------------------------------------------------------------
// Flash attention v8 == R6's attn_v6 body (PASSING) with ONLY the grid
// mapping changed: 1D grid + bijective XCD swizzle so all 16 q-tiles of one
// (b,h) land on one XCD -> K/V stay L2-resident (per-XCD footprint 4 MB).
// Everything else (LDS staging + T2 chunk-XOR swizzle, T14 prefetch,
// 2-barrier publish, swapped QK^T, base-2 softmax, defer-max) is unchanged.
// ---------------------------------------------------------------------------
__global__ __launch_bounds__(256) void attn_v8(
    const unsigned short* __restrict__ Qp, const unsigned short* __restrict__ Kp,
    const unsigned short* __restrict__ Vt, unsigned short* __restrict__ Y)
{
    __shared__ __align__(16) unsigned short Ks[64 * 64];
    __shared__ __align__(16) unsigned short Vs[64 * 64];   // rows are d, cols k
    __shared__ __align__(16) unsigned short Ps[4][16][72]; // per-wave P [q][k]
    const int tid  = threadIdx.x;
    const int lane = tid & 63;
    const int w    = tid >> 6;
    // ---- bijective XCD swizzle: 2048 blocks, 256/XCD, (b,h) contiguous ----
    const int flat    = blockIdx.x;                 // 0..2047
    const int logical = (flat & 7) * 256 + (flat >> 3);
    const int qt = logical & 15;                    // q-tile 0..15 (64 rows)
    const int bh = logical >> 4;                    // 0..127
    const int q0 = qt * 64;
    const size_t base = (size_t)bh * (SS * DK);
    const int lr = lane & 15, lg = lane >> 4;
    const int lg4 = lg * 4;

    // staging geometry: two 16B chunks per thread (tile = 512 chunks)
    const int c0 = tid,       r0 = c0 >> 3, h0 = c0 & 7;
    const int c1 = 256 + tid, r1 = c1 >> 3, h1 = c1 & 7;
    const int lds0 = r0 * 64 + ((h0 ^ (r0 & 7)) << 3);   // swizzled ushort idx
    const int lds1 = r1 * 64 + ((h1 ^ (r1 & 7)) << 3);

    // ---- K/V tile 0 -> regs -> LDS ----
    const unsigned short* kbase = Kp + base;
    const unsigned short* vbase = Vt + base;
    bf16x8 kA = *(const bf16x8*)(kbase + (size_t)r0 * DK + h0 * 8);
    bf16x8 kB = *(const bf16x8*)(kbase + (size_t)r1 * DK + h1 * 8);
    bf16x8 vA = *(const bf16x8*)(vbase + (size_t)r0 * SS + h0 * 8);
    bf16x8 vB = *(const bf16x8*)(vbase + (size_t)r1 * SS + h1 * 8);
    *(bf16x8*)&Ks[lds0] = kA; *(bf16x8*)&Ks[lds1] = kB;
    *(bf16x8*)&Vs[lds0] = vA; *(bf16x8*)&Vs[lds1] = vB;

    // ---- Q fragments direct from global (loop-invariant) ----
    const unsigned short* qptr = Qp + base + (size_t)(q0 + w * 16 + lr) * DK + lg * 8;
    const bf16x8 bQ0 = *(const bf16x8*)qptr;
    const bf16x8 bQ1 = *(const bf16x8*)(qptr + 32);

    __syncthreads();

    float m = -1e30f, l = 0.0f;       // per-lane state for q = lr (x4 copies)
    f32x4 oacc[4] = {};               // O[q=lg4+r][d=16*d0+lr]

    for (int kt = 0; kt < 16; ++kt) {
        // --- T14: issue next tile's global loads before compute ---
        if (kt < 15) {
            const int s1 = (kt + 1) * 64;
            kA = *(const bf16x8*)(kbase + (size_t)(s1 + r0) * DK + h0 * 8);
            kB = *(const bf16x8*)(kbase + (size_t)(s1 + r1) * DK + h1 * 8);
            vA = *(const bf16x8*)(vbase + (size_t)r0 * SS + s1 + h0 * 8);
            vB = *(const bf16x8*)(vbase + (size_t)r1 * SS + s1 + h1 * 8);
        }

        // --- QK^T (swapped): sacc[nb] = S^T[16 k-rows][16 q] ---
        f32x4 sacc[4];
        #pragma unroll
        for (int nb = 0; nb < 4; ++nb) {
            const int krow = nb * 16 + lr;
            const bf16x8 aK0 = *(const bf16x8*)&Ks[krow * 64 + ((lg       ^ (lr & 7)) << 3)];
            const bf16x8 aK1 = *(const bf16x8*)&Ks[krow * 64 + (((4 + lg) ^ (lr & 7)) << 3)];
            f32x4 z = {};
            z = __builtin_amdgcn_mfma_f32_16x16x32_bf16(aK0, bQ0, z, 0, 0, 0);
            z = __builtin_amdgcn_mfma_f32_16x16x32_bf16(aK1, bQ1, z, 0, 0, 0);
            sacc[nb] = z;
        }

        // --- V fragments (swizzled read; independent of softmax) ---
        bf16x8 bV[2][4];
        #pragma unroll
        for (int kk = 0; kk < 2; ++kk)
            #pragma unroll
            for (int d0 = 0; d0 < 4; ++d0) {
                const int vrow = d0 * 16 + lr;
                bV[kk][d0] = *(const bf16x8*)&Vs[vrow * 64 + (((kk * 4 + lg) ^ (lr & 7)) << 3)];
            }

        // --- online softmax over k (base-2; scale pre-folded into Q) ---
        float mx = sacc[0][0];
        #pragma unroll
        for (int nb = 0; nb < 4; ++nb)
            #pragma unroll
            for (int r = 0; r < 4; ++r)
                mx = fmaxf(mx, sacc[nb][r]);
        mx = fmaxf(mx, __shfl_xor(mx, 16));
        mx = fmaxf(mx, __shfl_xor(mx, 32));

        if (__any(mx > m + 8.0f)) {            // T13 defer-max, THR=8 (base-2)
            const float mn = fmaxf(m, mx);
            const float alpha = exp2_hw(m - mn);
            m = mn;
            l *= alpha;
            #pragma unroll
            for (int r = 0; r < 4; ++r) {
                const float ar = __shfl(alpha, lg4 + r, 16);
                #pragma unroll
                for (int d0 = 0; d0 < 4; ++d0) oacc[d0][r] *= ar;
            }
        }

        float p[4][4];
        float ls = 0.0f;
        #pragma unroll
        for (int nb = 0; nb < 4; ++nb)
            #pragma unroll
            for (int r = 0; r < 4; ++r) {
                const float pv = exp2_hw(sacc[nb][r] - m);
                p[nb][r] = pv;
                ls += pv;
            }
        ls += __shfl_xor(ls, 16);
        ls += __shfl_xor(ls, 32);
        l += ls;

        // --- pack P to bf16, wide LDS stores: P[q=lr][k=16nb+lg4 .. +3] ---
        #pragma unroll
        for (int nb = 0; nb < 4; ++nb) {
            uint2 pw;
            pw.x = cvt_pk_bf16(p[nb][0], p[nb][1]);
            pw.y = cvt_pk_bf16(p[nb][2], p[nb][3]);
            *(uint2*)&Ps[w][lr][nb * 16 + lg4] = pw;
        }
        // same-wave write->read: compiler inserts lgkmcnt wait, no barrier

        // --- PV: O[16q][64d] += P[16][64] x V[64][64] ---
        #pragma unroll
        for (int kk = 0; kk < 2; ++kk) {
            const bf16x8 aP = *(const bf16x8*)&Ps[w][lr][kk * 32 + lg * 8];
            #pragma unroll
            for (int d0 = 0; d0 < 4; ++d0)
                oacc[d0] = __builtin_amdgcn_mfma_f32_16x16x32_bf16(aP, bV[kk][d0], oacc[d0], 0, 0, 0);
        }

        // --- T14 tail: publish prefetched tile to LDS ---
        if (kt < 15) {
            __syncthreads();                   // all waves done reading tiles
            *(bf16x8*)&Ks[lds0] = kA; *(bf16x8*)&Ks[lds1] = kB;
            *(bf16x8*)&Vs[lds0] = vA; *(bf16x8*)&Vs[lds1] = vB;
            __syncthreads();                   // tiles ready
        }
    }

    // epilogue: Y[b][s][h*64+d] bf16; 1/l broadcast per row
    const float linv = 1.0f / l;
    const int hh = bh & 15, bb = bh >> 4;
    #pragma unroll
    for (int r = 0; r < 4; ++r) {
        const float lri = __shfl(linv, lg4 + r, 16);
        const int qr = q0 + w * 16 + lg4 + r;
        unsigned short* dst = Y + (size_t)(bb * SS + qr) * EE + hh * DK;
        #pragma unroll
        for (int d0 = 0; d0 < 4; ++d0)
            dst[d0 * 16 + lr] = f2bf(oacc[d0][r] * lri);
    }
}

// ---------------------------------------------------------------------------
// MLP GEMM, bf16 MFMA, m97-structure: C = A[M,K] @ B[N,K]^T + bias (+ReLU)
// 128x128 tile, 4 waves (2x2 of 64x64), K-step 64, LINEAR LDS staged via
// global_load_lds width=16. 1D grid + bijective XCD swizzle (A-tile L2 reuse).
// ---------------------------------------------------------------------------
template<bool RELU, bool OUT_BF16>
__global__ __launch_bounds__(256) void mlp_gemm(
    const unsigned short* __restrict__ A, const unsigned short* __restrict__ B,
    const float* __restrict__ bias, void* __restrict__ Cv)
{
    constexpr int K = 1024, N = 1024;
    __shared__ __align__(16) unsigned short As[128 * 64];
    __shared__ __align__(16) unsigned short Bs[128 * 64];
    const int tid  = threadIdx.x;
    const int lane = tid & 63;
    const int w = tid >> 6, wm = w >> 1, wn = w & 1;
    // bijective XCD swizzle: 512 blocks, 64/XCD = 8 M-tiles x 8 N-tiles
    const int flat    = blockIdx.x;
    const int logical = (flat & 7) * 64 + (flat >> 3);
    const int n0 = (logical & 7) * 128, m0 = (logical >> 3) * 128;
    const int lr = lane & 15, lg = lane >> 4;

    f32x4 acc[4][4] = {};

    for (int kt = 0; kt < K; kt += 64) {
        __syncthreads();                       // previous tile's readers done
        #pragma unroll
        for (int p = 0; p < 4; ++p) {
            const int c = p * 256 + tid;       // chunk 0..1023
            const int row = c >> 3, col = (c & 7) * 8;
            const int lb = (p * 256 + (tid & ~63)) * 8;   // wave-uniform LDS base
            gld16(A + (size_t)(m0 + row) * K + kt + col, As + lb);
            gld16(B + (size_t)(n0 + row) * K + kt + col, Bs + lb);
        }
        __syncthreads();                       // vmcnt(0) drain + publish
        #pragma unroll
        for (int kk = 0; kk < 2; ++kk) {
            bf16x8 af[4], bfr[4];
            #pragma unroll
            for (int mf = 0; mf < 4; ++mf)
                af[mf] = *(const bf16x8*)&As[(wm * 64 + mf * 16 + lr) * 64 + kk * 32 + lg * 8];
            #pragma unroll
            for (int nf = 0; nf < 4; ++nf)
                bfr[nf] = *(const bf16x8*)&Bs[(wn * 64 + nf * 16 + lr) * 64 + kk * 32 + lg * 8];
            #pragma unroll
            for (int mf = 0; mf < 4; ++mf)
                #pragma unroll
                for (int nf = 0; nf < 4; ++nf)
                    acc[mf][nf] = __builtin_amdgcn_mfma_f32_16x16x32_bf16(
                        af[mf], bfr[nf], acc[mf][nf], 0, 0, 0);
        }
    }

    #pragma unroll
    for (int nf = 0; nf < 4; ++nf) {
        const int cc = n0 + wn * 64 + nf * 16 + lr;
        const float bb = bias[cc];
        #pragma unroll
        for (int mf = 0; mf < 4; ++mf) {
            #pragma unroll
            for (int r = 0; r < 4; ++r) {
                float x = acc[mf][nf][r] + bb;
                if (RELU) x = fmaxf(x, 0.0f);
                const size_t rr = (size_t)(m0 + wm * 64 + mf * 16 + lg * 4 + r);
                if (OUT_BF16) ((unsigned short*)Cv)[rr * N + cc] = f2bf(x);
                else          ((float*)Cv)[rr * N + cc] = x;
            }
        }
    }
}

// ---------------------------------------------------------------------------
// Workspace layout (ushort elements):
//   Qp : [0        , 8388608 )  -> reused as H1 after attention
//   Kp : [8388608  , 16777216)
//   Vt : [16777216 , 25165824)  (projection z=2 writes [b][h][d][s] directly)
//   Y  : [25165824 , 33554432)
//   W1b: [33554432 , 34603008)
//   W2b: [34603008 , 35651584)
//   qb : [35651584 , 36175872)
//   kb : [36175872 , 36700160)
//   vb : [36700160 , 37224448)
//   Wqb: [37224448 , 37289984)   total ~74.6 MB
// ---------------------------------------------------------------------------
extern "C" void kernel_launch(void* const* d_in, const int* in_sizes, int n_in,
                              void* d_out, int out_size, void* d_ws, size_t ws_size,
                              hipStream_t stream) {
    const float* q  = (const float*)d_in[0];
    const float* k  = (const float*)d_in[1];
    const float* v  = (const float*)d_in[2];
    const float* Wq = (const float*)d_in[3];
    const float* bq = (const float*)d_in[4];
    const float* W1 = (const float*)d_in[5];
    const float* b1 = (const float*)d_in[6];
    const float* W2 = (const float*)d_in[7];
    const float* b2 = (const float*)d_in[8];

    unsigned short* wsu = (unsigned short*)d_ws;
    unsigned short* Qp  = wsu;
    unsigned short* Kp  = wsu + (size_t)8388608;
    unsigned short* Vt  = wsu + (size_t)16777216;
    unsigned short* Y   = wsu + (size_t)25165824;
    unsigned short* W1b = wsu + (size_t)33554432;
    unsigned short* W2b = wsu + (size_t)34603008;
    unsigned short* qb  = wsu + (size_t)35651584;
    unsigned short* kb  = wsu + (size_t)36175872;
    unsigned short* vb  = wsu + (size_t)36700160;
    unsigned short* Wqb = wsu + (size_t)37224448;
    unsigned short* H1  = Qp;   // Qp dead after attention

    dim3 blk(256);

    cvt_all<<<dim3(512, 6), blk, 0, stream>>>(W1, W2, q, k, v, Wq,
                                              W1b, W2b, qb, kb, vb, Wqb);

    // folds 1/sqrt(dk)=0.125 and log2(e) into Q so attn uses v_exp_f32 directly
    const float qscale = 0.125f * 1.44269504088896340736f;
    proj_mfma<<<dim3(8, 64, 3), blk, 0, stream>>>(qb, kb, vb, Wqb, bq, Qp, qscale);

    attn_v8<<<2048, blk, 0, stream>>>(Qp, Kp, Vt, Y);

    mlp_gemm<true,  true ><<<512, blk, 0, stream>>>(Y,  W1b, b1, H1);
    mlp_gemm<false, false><<<512, blk, 0, stream>>>(H1, W2b, b2, d_out);
}

// Round 9
// 152.776 us; speedup vs baseline: 1.0356x; 1.0355x over previous
//
#include <hip/hip_runtime.h>
#include <math.h>

// Problem constants (MultiHeadAttention_15341623181946)
#define NB 8          // batch
#define SS 1024       // sequence
#define NH 16         // heads
#define DK 64         // head dim
#define EE 1024       // NH*DK
#define DMOD 1024     // d_model

using bf16x8 = __attribute__((ext_vector_type(8))) short;   // 8 bf16 = 4 VGPR
using f32x4  = __attribute__((ext_vector_type(4))) float;   // MFMA acc

__device__ __forceinline__ unsigned short f2bf(float f) {
    unsigned u = __builtin_bit_cast(unsigned, f);
    u += 0x7FFFu + ((u >> 16) & 1u);        // round-to-nearest-even
    return (unsigned short)(u >> 16);
}

__device__ __forceinline__ float exp2_hw(float x) {
#if __has_builtin(__builtin_amdgcn_exp2f)
    return __builtin_amdgcn_exp2f(x);
#else
    float r; asm("v_exp_f32 %0, %1" : "=v"(r) : "v"(x)); return r;
#endif
}

__device__ __forceinline__ unsigned cvt_pk_bf16(float lo, float hi) {
    unsigned r;
    asm("v_cvt_pk_bf16_f32 %0, %1, %2" : "=v"(r) : "v"(lo), "v"(hi));
    return r;
}

// Async global->LDS, 16B per lane. LDS dest must be wave-uniform base;
// HW writes base + lane*16. Global src is per-lane.
__device__ __forceinline__ void gld16(const void* g, void* l) {
    __builtin_amdgcn_global_load_lds(
        (const __attribute__((address_space(1))) void*)g,
        (__attribute__((address_space(3))) void*)l, 16, 0, 0);
}

// ---------------------------------------------------------------------------
// Batched f32 -> bf16 conversion for all tensors that feed MFMA.
// z: 0=W1(1M) 1=W2(1M) 2=q(512K) 3=k 4=v 5=Wq(64K). grid (512, 6).
// ---------------------------------------------------------------------------
__global__ __launch_bounds__(256) void cvt_all(
    const float* __restrict__ W1, const float* __restrict__ W2,
    const float* __restrict__ q, const float* __restrict__ k,
    const float* __restrict__ v, const float* __restrict__ Wq,
    unsigned short* __restrict__ W1b, unsigned short* __restrict__ W2b,
    unsigned short* __restrict__ qb, unsigned short* __restrict__ kb,
    unsigned short* __restrict__ vb, unsigned short* __restrict__ Wqb)
{
    const int z = blockIdx.y;
    const float* s; unsigned short* d; int n;
    switch (z) {
        case 0:  s = W1; d = W1b; n = 1048576; break;
        case 1:  s = W2; d = W2b; n = 1048576; break;
        case 2:  s = q;  d = qb;  n = 524288;  break;
        case 3:  s = k;  d = kb;  n = 524288;  break;
        case 4:  s = v;  d = vb;  n = 524288;  break;
        default: s = Wq; d = Wqb; n = 65536;   break;
    }
    const int i = (blockIdx.x * 256 + threadIdx.x) * 8;
    if (i >= n) return;
    const float4 a = *(const float4*)(s + i);
    const float4 b = *(const float4*)(s + i + 4);
    bf16x8 o;
    o[0]=(short)f2bf(a.x); o[1]=(short)f2bf(a.y); o[2]=(short)f2bf(a.z); o[3]=(short)f2bf(a.w);
    o[4]=(short)f2bf(b.x); o[5]=(short)f2bf(b.y); o[6]=(short)f2bf(b.z); o[7]=(short)f2bf(b.w);
    *(bf16x8*)(d + i) = o;
}

// ---------------------------------------------------------------------------
// Projection GEMM, bf16 MFMA, K=64. z = 0:q (scaled), 1:k, 2:v (TRANSPOSED).
// z<2 : C[b][h][s][d]  = (X @ Wq^T + bq) * sc
// z==2: C[b][h][d][s]  =  X @ Wq^T + bq        (V stored pre-transposed)
// 128x128 tile, 4 waves (2x2 of 64x64), single K-step, global_load_lds stage.
// ---------------------------------------------------------------------------
__global__ __launch_bounds__(256) void proj_mfma(
    const unsigned short* __restrict__ qb, const unsigned short* __restrict__ kb,
    const unsigned short* __restrict__ vb, const unsigned short* __restrict__ Wb,
    const float* __restrict__ bias, unsigned short* __restrict__ Cbase,
    float qscale)
{
    __shared__ __align__(16) unsigned short As[128 * 64];
    __shared__ __align__(16) unsigned short Bs[128 * 64];
    const int z = blockIdx.z;
    const unsigned short* X = (z == 0) ? qb : (z == 1) ? kb : vb;
    unsigned short* C = Cbase + (size_t)z * 8388608;
    const float sc = (z == 0) ? qscale : 1.0f;
    const int tid  = threadIdx.x;
    const int lane = tid & 63;
    const int w = tid >> 6, wm = w >> 1, wn = w & 1;
    const int n0 = blockIdx.x * 128, m0 = blockIdx.y * 128;
    const int lr = lane & 15, lg = lane >> 4;

    #pragma unroll
    for (int p = 0; p < 4; ++p) {
        const int c = p * 256 + tid;
        const int lb = (p * 256 + (tid & ~63)) * 8;   // wave-uniform LDS elem base
        gld16(X  + (size_t)m0 * DK + (size_t)c * 8, As + lb);
        gld16(Wb + (size_t)n0 * DK + (size_t)c * 8, Bs + lb);
    }
    __syncthreads();

    f32x4 acc[4][4] = {};
    #pragma unroll
    for (int kk = 0; kk < 2; ++kk) {
        bf16x8 af[4], bfr[4];
        #pragma unroll
        for (int mf = 0; mf < 4; ++mf)
            af[mf] = *(const bf16x8*)&As[(wm * 64 + mf * 16 + lr) * 64 + kk * 32 + lg * 8];
        #pragma unroll
        for (int nf = 0; nf < 4; ++nf)
            bfr[nf] = *(const bf16x8*)&Bs[(wn * 64 + nf * 16 + lr) * 64 + kk * 32 + lg * 8];
        #pragma unroll
        for (int mf = 0; mf < 4; ++mf)
            #pragma unroll
            for (int nf = 0; nf < 4; ++nf)
                acc[mf][nf] = __builtin_amdgcn_mfma_f32_16x16x32_bf16(
                    af[mf], bfr[nf], acc[mf][nf], 0, 0, 0);
    }

    #pragma unroll
    for (int nf = 0; nf < 4; ++nf) {
        const int n = n0 + wn * 64 + nf * 16 + lr;
        const float bb = bias[n];
        #pragma unroll
        for (int mf = 0; mf < 4; ++mf)
            #pragma unroll
            for (int r = 0; r < 4; ++r) {
                const int mr = m0 + wm * 64 + mf * 16 + lg * 4 + r;
                const int bh = (mr >> 10) * NH + (n >> 6);
                const int s  = mr & 1023, d = n & 63;
                const size_t idx = (z == 2)
                    ? (size_t)bh * 65536 + (size_t)d * 1024 + s     // [b][h][d][s]
                    : (size_t)bh * 65536 + (size_t)s * 64 + d;      // [b][h][s][d]
                C[idx] = f2bf((acc[mf][nf][r] + bb) * sc);
            }
    }
}

// ---------------------------------------------------------------------------
// Flash attention v9: R8's verified body widened to 32 q-rows PER WAVE
// (QBLK=128, 4 waves, grid 1024). Same 2-barrier publish, T2 chunk-XOR
// swizzle, T14 prefetch, swapped QK^T, base-2 softmax, defer-max, XCD
// swizzle. The two 16-row q-groups (qf=0,1) amortize every K/V LDS read and
// interleave their independent softmax chains (ILP on the serial path);
// bV fragments are read once and feed both PV halves.
// ---------------------------------------------------------------------------
__global__ __launch_bounds__(256) void attn_v9(
    const unsigned short* __restrict__ Qp, const unsigned short* __restrict__ Kp,
    const unsigned short* __restrict__ Vt, unsigned short* __restrict__ Y)
{
    __shared__ __align__(16) unsigned short Ks[64 * 64];
    __shared__ __align__(16) unsigned short Vs[64 * 64];   // rows are d, cols k
    __shared__ __align__(16) unsigned short Ps[4][32][72]; // per-wave P [q][k]
    const int tid  = threadIdx.x;
    const int lane = tid & 63;
    const int w    = tid >> 6;
    // ---- bijective XCD swizzle: 1024 blocks, 128/XCD, (b,h) contiguous ----
    const int flat    = blockIdx.x;                 // 0..1023
    const int logical = (flat & 7) * 128 + (flat >> 3);
    const int qt = logical & 7;                     // q-tile 0..7 (128 rows)
    const int bh = logical >> 3;                    // 0..127
    const int q0 = qt * 128;
    const size_t base = (size_t)bh * (SS * DK);
    const int lr = lane & 15, lg = lane >> 4;
    const int lg4 = lg * 4;

    // staging geometry: two 16B chunks per thread (tile = 512 chunks)
    const int c0 = tid,       r0 = c0 >> 3, h0 = c0 & 7;
    const int c1 = 256 + tid, r1 = c1 >> 3, h1 = c1 & 7;
    const int lds0 = r0 * 64 + ((h0 ^ (r0 & 7)) << 3);   // swizzled ushort idx
    const int lds1 = r1 * 64 + ((h1 ^ (r1 & 7)) << 3);

    // ---- K/V tile 0 -> regs -> LDS ----
    const unsigned short* kbase = Kp + base;
    const unsigned short* vbase = Vt + base;
    bf16x8 kA = *(const bf16x8*)(kbase + (size_t)r0 * DK + h0 * 8);
    bf16x8 kB = *(const bf16x8*)(kbase + (size_t)r1 * DK + h1 * 8);
    bf16x8 vA = *(const bf16x8*)(vbase + (size_t)r0 * SS + h0 * 8);
    bf16x8 vB = *(const bf16x8*)(vbase + (size_t)r1 * SS + h1 * 8);
    *(bf16x8*)&Ks[lds0] = kA; *(bf16x8*)&Ks[lds1] = kB;
    *(bf16x8*)&Vs[lds0] = vA; *(bf16x8*)&Vs[lds1] = vB;

    // ---- Q fragments direct from global (loop-invariant), 2 q-groups ----
    bf16x8 bQ[2][2];
    #pragma unroll
    for (int qf = 0; qf < 2; ++qf) {
        const unsigned short* qptr =
            Qp + base + (size_t)(q0 + w * 32 + qf * 16 + lr) * DK + lg * 8;
        bQ[qf][0] = *(const bf16x8*)qptr;
        bQ[qf][1] = *(const bf16x8*)(qptr + 32);
    }

    __syncthreads();

    float m[2] = {-1e30f, -1e30f}, l[2] = {0.0f, 0.0f};
    f32x4 oacc[2][4] = {};            // [qf][d0], row r -> q = qf*16+lg4+r

    for (int kt = 0; kt < 16; ++kt) {
        // --- T14: issue next tile's global loads before compute ---
        if (kt < 15) {
            const int s1 = (kt + 1) * 64;
            kA = *(const bf16x8*)(kbase + (size_t)(s1 + r0) * DK + h0 * 8);
            kB = *(const bf16x8*)(kbase + (size_t)(s1 + r1) * DK + h1 * 8);
            vA = *(const bf16x8*)(vbase + (size_t)r0 * SS + s1 + h0 * 8);
            vB = *(const bf16x8*)(vbase + (size_t)r1 * SS + s1 + h1 * 8);
        }

        // --- QK^T (swapped) for both q-groups: sacc[qf][nb] = S^T[16k][16q] ---
        f32x4 sacc[2][4];
        #pragma unroll
        for (int nb = 0; nb < 4; ++nb) {
            const int krow = nb * 16 + lr;
            const bf16x8 aK0 = *(const bf16x8*)&Ks[krow * 64 + ((lg       ^ (lr & 7)) << 3)];
            const bf16x8 aK1 = *(const bf16x8*)&Ks[krow * 64 + (((4 + lg) ^ (lr & 7)) << 3)];
            #pragma unroll
            for (int qf = 0; qf < 2; ++qf) {
                f32x4 z = {};
                z = __builtin_amdgcn_mfma_f32_16x16x32_bf16(aK0, bQ[qf][0], z, 0, 0, 0);
                z = __builtin_amdgcn_mfma_f32_16x16x32_bf16(aK1, bQ[qf][1], z, 0, 0, 0);
                sacc[qf][nb] = z;
            }
        }

        // --- V fragments (read once, feed both PV halves) ---
        bf16x8 bV[2][4];
        #pragma unroll
        for (int kk = 0; kk < 2; ++kk)
            #pragma unroll
            for (int d0 = 0; d0 < 4; ++d0) {
                const int vrow = d0 * 16 + lr;
                bV[kk][d0] = *(const bf16x8*)&Vs[vrow * 64 + (((kk * 4 + lg) ^ (lr & 7)) << 3)];
            }

        // --- per-group online softmax + PV (independent chains -> ILP) ---
        #pragma unroll
        for (int qf = 0; qf < 2; ++qf) {
            float mx = sacc[qf][0][0];
            #pragma unroll
            for (int nb = 0; nb < 4; ++nb)
                #pragma unroll
                for (int r = 0; r < 4; ++r)
                    mx = fmaxf(mx, sacc[qf][nb][r]);
            mx = fmaxf(mx, __shfl_xor(mx, 16));
            mx = fmaxf(mx, __shfl_xor(mx, 32));

            if (__any(mx > m[qf] + 8.0f)) {    // T13 defer-max, THR=8 (base-2)
                const float mn = fmaxf(m[qf], mx);
                const float alpha = exp2_hw(m[qf] - mn);
                m[qf] = mn;
                l[qf] *= alpha;
                #pragma unroll
                for (int r = 0; r < 4; ++r) {
                    const float ar = __shfl(alpha, lg4 + r, 16);
                    #pragma unroll
                    for (int d0 = 0; d0 < 4; ++d0) oacc[qf][d0][r] *= ar;
                }
            }

            float p[4][4];
            float ls = 0.0f;
            #pragma unroll
            for (int nb = 0; nb < 4; ++nb)
                #pragma unroll
                for (int r = 0; r < 4; ++r) {
                    const float pv = exp2_hw(sacc[qf][nb][r] - m[qf]);
                    p[nb][r] = pv;
                    ls += pv;
                }
            ls += __shfl_xor(ls, 16);
            ls += __shfl_xor(ls, 32);
            l[qf] += ls;

            // pack P -> LDS rows qf*16 + q
            #pragma unroll
            for (int nb = 0; nb < 4; ++nb) {
                uint2 pw;
                pw.x = cvt_pk_bf16(p[nb][0], p[nb][1]);
                pw.y = cvt_pk_bf16(p[nb][2], p[nb][3]);
                *(uint2*)&Ps[w][qf * 16 + lr][nb * 16 + lg4] = pw;
            }
            // same-wave write->read: in-order LDS + compiler lgkmcnt

            // PV: O[16q][64d] += P[16][64] x V[64][64]
            #pragma unroll
            for (int kk = 0; kk < 2; ++kk) {
                const bf16x8 aP = *(const bf16x8*)&Ps[w][qf * 16 + lr][kk * 32 + lg * 8];
                #pragma unroll
                for (int d0 = 0; d0 < 4; ++d0)
                    oacc[qf][d0] = __builtin_amdgcn_mfma_f32_16x16x32_bf16(
                        aP, bV[kk][d0], oacc[qf][d0], 0, 0, 0);
            }
        }

        // --- T14 tail: publish prefetched tile to LDS ---
        if (kt < 15) {
            __syncthreads();                   // all waves done reading tiles
            *(bf16x8*)&Ks[lds0] = kA; *(bf16x8*)&Ks[lds1] = kB;
            *(bf16x8*)&Vs[lds0] = vA; *(bf16x8*)&Vs[lds1] = vB;
            __syncthreads();                   // tiles ready
        }
    }

    // epilogue: Y[b][s][h*64+d] bf16; 1/l broadcast per row
    const int hh = bh & 15, bb = bh >> 4;
    #pragma unroll
    for (int qf = 0; qf < 2; ++qf) {
        const float linv = 1.0f / l[qf];
        #pragma unroll
        for (int r = 0; r < 4; ++r) {
            const float lri = __shfl(linv, lg4 + r, 16);
            const int qr = q0 + w * 32 + qf * 16 + lg4 + r;
            unsigned short* dst = Y + (size_t)(bb * SS + qr) * EE + hh * DK;
            #pragma unroll
            for (int d0 = 0; d0 < 4; ++d0)
                dst[d0 * 16 + lr] = f2bf(oacc[qf][d0][r] * lri);
        }
    }
}

// ---------------------------------------------------------------------------
// MLP GEMM, bf16 MFMA, m97-structure: C = A[M,K] @ B[N,K]^T + bias (+ReLU)
// 128x128 tile, 4 waves (2x2 of 64x64), K-step 64, LINEAR LDS staged via
// global_load_lds width=16. 1D grid + bijective XCD swizzle (A-tile L2 reuse).
// ---------------------------------------------------------------------------
template<bool RELU, bool OUT_BF16>
__global__ __launch_bounds__(256) void mlp_gemm(
    const unsigned short* __restrict__ A, const unsigned short* __restrict__ B,
    const float* __restrict__ bias, void* __restrict__ Cv)
{
    constexpr int K = 1024, N = 1024;
    __shared__ __align__(16) unsigned short As[128 * 64];
    __shared__ __align__(16) unsigned short Bs[128 * 64];
    const int tid  = threadIdx.x;
    const int lane = tid & 63;
    const int w = tid >> 6, wm = w >> 1, wn = w & 1;
    // bijective XCD swizzle: 512 blocks, 64/XCD = 8 M-tiles x 8 N-tiles
    const int flat    = blockIdx.x;
    const int logical = (flat & 7) * 64 + (flat >> 3);
    const int n0 = (logical & 7) * 128, m0 = (logical >> 3) * 128;
    const int lr = lane & 15, lg = lane >> 4;

    f32x4 acc[4][4] = {};

    for (int kt = 0; kt < K; kt += 64) {
        __syncthreads();                       // previous tile's readers done
        #pragma unroll
        for (int p = 0; p < 4; ++p) {
            const int c = p * 256 + tid;       // chunk 0..1023
            const int row = c >> 3, col = (c & 7) * 8;
            const int lb = (p * 256 + (tid & ~63)) * 8;   // wave-uniform LDS base
            gld16(A + (size_t)(m0 + row) * K + kt + col, As + lb);
            gld16(B + (size_t)(n0 + row) * K + kt + col, Bs + lb);
        }
        __syncthreads();                       // vmcnt(0) drain + publish
        #pragma unroll
        for (int kk = 0; kk < 2; ++kk) {
            bf16x8 af[4], bfr[4];
            #pragma unroll
            for (int mf = 0; mf < 4; ++mf)
                af[mf] = *(const bf16x8*)&As[(wm * 64 + mf * 16 + lr) * 64 + kk * 32 + lg * 8];
            #pragma unroll
            for (int nf = 0; nf < 4; ++nf)
                bfr[nf] = *(const bf16x8*)&Bs[(wn * 64 + nf * 16 + lr) * 64 + kk * 32 + lg * 8];
            #pragma unroll
            for (int mf = 0; mf < 4; ++mf)
                #pragma unroll
                for (int nf = 0; nf < 4; ++nf)
                    acc[mf][nf] = __builtin_amdgcn_mfma_f32_16x16x32_bf16(
                        af[mf], bfr[nf], acc[mf][nf], 0, 0, 0);
        }
    }

    #pragma unroll
    for (int nf = 0; nf < 4; ++nf) {
        const int cc = n0 + wn * 64 + nf * 16 + lr;
        const float bb = bias[cc];
        #pragma unroll
        for (int mf = 0; mf < 4; ++mf) {
            #pragma unroll
            for (int r = 0; r < 4; ++r) {
                float x = acc[mf][nf][r] + bb;
                if (RELU) x = fmaxf(x, 0.0f);
                const size_t rr = (size_t)(m0 + wm * 64 + mf * 16 + lg * 4 + r);
                if (OUT_BF16) ((unsigned short*)Cv)[rr * N + cc] = f2bf(x);
                else          ((float*)Cv)[rr * N + cc] = x;
            }
        }
    }
}

// ---------------------------------------------------------------------------
// Workspace layout (ushort elements):
//   Qp : [0        , 8388608 )  -> reused as H1 after attention
//   Kp : [8388608  , 16777216)
//   Vt : [16777216 , 25165824)  (projection z=2 writes [b][h][d][s] directly)
//   Y  : [25165824 , 33554432)
//   W1b: [33554432 , 34603008)
//   W2b: [34603008 , 35651584)
//   qb : [35651584 , 36175872)
//   kb : [36175872 , 36700160)
//   vb : [36700160 , 37224448)
//   Wqb: [37224448 , 37289984)   total ~74.6 MB
// ---------------------------------------------------------------------------
extern "C" void kernel_launch(void* const* d_in, const int* in_sizes, int n_in,
                              void* d_out, int out_size, void* d_ws, size_t ws_size,
                              hipStream_t stream) {
    const float* q  = (const float*)d_in[0];
    const float* k  = (const float*)d_in[1];
    const float* v  = (const float*)d_in[2];
    const float* Wq = (const float*)d_in[3];
    const float* bq = (const float*)d_in[4];
    const float* W1 = (const float*)d_in[5];
    const float* b1 = (const float*)d_in[6];
    const float* W2 = (const float*)d_in[7];
    const float* b2 = (const float*)d_in[8];

    unsigned short* wsu = (unsigned short*)d_ws;
    unsigned short* Qp  = wsu;
    unsigned short* Kp  = wsu + (size_t)8388608;
    unsigned short* Vt  = wsu + (size_t)16777216;
    unsigned short* Y   = wsu + (size_t)25165824;
    unsigned short* W1b = wsu + (size_t)33554432;
    unsigned short* W2b = wsu + (size_t)34603008;
    unsigned short* qb  = wsu + (size_t)35651584;
    unsigned short* kb  = wsu + (size_t)36175872;
    unsigned short* vb  = wsu + (size_t)36700160;
    unsigned short* Wqb = wsu + (size_t)37224448;
    unsigned short* H1  = Qp;   // Qp dead after attention

    dim3 blk(256);

    cvt_all<<<dim3(512, 6), blk, 0, stream>>>(W1, W2, q, k, v, Wq,
                                              W1b, W2b, qb, kb, vb, Wqb);

    // folds 1/sqrt(dk)=0.125 and log2(e) into Q so attn uses v_exp_f32 directly
    const float qscale = 0.125f * 1.44269504088896340736f;
    proj_mfma<<<dim3(8, 64, 3), blk, 0, stream>>>(qb, kb, vb, Wqb, bq, Qp, qscale);

    attn_v9<<<1024, blk, 0, stream>>>(Qp, Kp, Vt, Y);

    mlp_gemm<true,  true ><<<512, blk, 0, stream>>>(Y,  W1b, b1, H1);
    mlp_gemm<false, false><<<512, blk, 0, stream>>>(H1, W2b, b2, d_out);
}